// Round 18
// baseline (73.984 us; speedup 1.0000x reference)
//
#include <hip/hip_runtime.h>

#define NN 100000
#define NE 1600000
#define DIM 64
#define K 782            // buckets of 128 nodes: b = dst >> 7
#define ABLK 6250        // edges per binning tile; NE = 256 * 6250 exactly
#define NTILE 256        // one binA block per CU
#define GCAP 2600        // fixed per-bucket capacity (mean 2048, sigma 45, 12+ sigma)
#define LSTR 132         // ldeg stride per bucket (129 used, padded)

typedef __attribute__((ext_vector_type(8))) short bf16x8;
typedef __attribute__((ext_vector_type(8))) _Float16 f16x8;
typedef __attribute__((ext_vector_type(2))) float f32x2;
typedef __attribute__((ext_vector_type(4))) float f32x4;

__device__ __forceinline__ unsigned short f2bf(float f) {
    union { float f; unsigned u; } c; c.f = f;
    unsigned r = (c.u + 0x7FFFu + ((c.u >> 16) & 1u)) >> 16;   // RNE
    return (unsigned short)r;
}
__device__ __forceinline__ unsigned short f2h(float f) {
    union { _Float16 h; unsigned short u; } c; c.h = (_Float16)f;
    return c.u;
}
__device__ __forceinline__ void acc8(uint2 v, float& a0, float& a1, float& a2, float& a3,
                                     float& a4, float& a5, float& a6, float& a7) {
    f32x2 d0 = __builtin_amdgcn_cvt_pk_f32_fp8(v.x, false);
    f32x2 d1 = __builtin_amdgcn_cvt_pk_f32_fp8(v.x, true);
    f32x2 d2 = __builtin_amdgcn_cvt_pk_f32_fp8(v.y, false);
    f32x2 d3 = __builtin_amdgcn_cvt_pk_f32_fp8(v.y, true);
    a0 += d0.x; a1 += d0.y; a2 += d1.x; a3 += d1.y;
    a4 += d2.x; a5 += d2.y; a6 += d3.x; a7 += d3.y;
}

// ---------------- init fixed bucket cursors ----------------

__global__ void k_init(int* __restrict__ gcur) {
    int i = blockIdx.x * blockDim.x + threadIdx.x;
    if (i < K) gcur[i] = 0;
}

// ---------------- Phase A: bin edges by bucket, coalesced run writes ----------------

__global__ __launch_bounds__(1024) void k_binA(const int* __restrict__ ei,
                                               int* __restrict__ gcur,
                                               unsigned* __restrict__ ebuf) {
    __shared__ int hist[1024];               // per-bucket counts (only [0..K) used)
    __shared__ int wsum[16];
    __shared__ int hoff[K];                  // run start within tile
    __shared__ int gbase[K];                 // claimed global base (absolute)
    __shared__ int lcur[K];
    __shared__ unsigned sbufE[ABLK];         // packed (ldst<<17)|src, bucket-sorted
    __shared__ unsigned short sbufB[ABLK];   // bucket id per entry

    const int tid = threadIdx.x;
    const int e0 = blockIdx.x * ABLK;

    hist[tid] = 0;
    __syncthreads();

    // pass 1: count (keep edges in registers); NE = NTILE*ABLK exactly
    int pk_[7]; int b_[7]; int myN = 0;
#pragma unroll
    for (int i = 0; i < 7; ++i) {
        int j = i * 1024 + tid;
        if (j < ABLK) {
            int e = e0 + j;
            int dst = ei[NE + e];
            int src = ei[e];
            int b = dst >> 7;
            pk_[myN]  = ((dst & 127) << 17) | src;
            b_[myN]   = b;
            ++myN;
            atomicAdd(&hist[b], 1);
        }
    }
    __syncthreads();

    // wave-level scan of hist (3 barriers total)
    const int lane = tid & 63;
    const int wid  = tid >> 6;
    int cntv = hist[tid];
    int v = cntv;
#pragma unroll
    for (int off = 1; off < 64; off <<= 1) {
        int t = __shfl_up(v, off);
        if (lane >= off) v += t;
    }
    if (lane == 63) wsum[wid] = v;
    __syncthreads();
    int woff = 0;
#pragma unroll
    for (int u = 0; u < 15; ++u) {
        if (u < wid) woff += wsum[u];
    }
    if (tid < K) {
        int incl = v + woff;
        int ho = incl - cntv;
        hoff[tid] = ho;
        lcur[tid] = ho;
        int claimed = (cntv > 0) ? atomicAdd(&gcur[tid], cntv) : 0;
        gbase[tid] = tid * GCAP + claimed;
    }
    __syncthreads();

    // pass 2: place into LDS, bucket-sorted
    for (int j = 0; j < myN; ++j) {
        int pos = atomicAdd(&lcur[b_[j]], 1);
        sbufE[pos] = (unsigned)pk_[j];
        sbufB[pos] = (unsigned short)b_[j];
    }
    __syncthreads();

    // pass 3: coalesced run writes
    for (int j = tid; j < ABLK; j += 1024) {
        unsigned en = sbufE[j];
        int b = sbufB[j];
        ebuf[gbase[b] + (j - hoff[b])] = en;
    }
}

// ---------------- MFMA dense, 1 block = 1 bucket (128 rows, 512 thr) ----------------
// Holds its ebuf slice in registers; histograms -> dinv; wave-0 scan -> lptr
// (LDS + 129-entry global ldeg); then places entries IN-PLACE back into the
// ebuf slice node-sorted (src17 only) so gatherB needs no prologue at all.
// Swizzled stores: position p = lr*4+ct  <->  col = (p&3)*16 + (p>>2).
// g8[r][p]  = fp8(dinv*xW col); lin[r][p] = f16(xWl + b + bl + dinv^2*xW col).

__global__ __launch_bounds__(512) void k_gemm(
    const float* __restrict__ x, const float* __restrict__ W,
    const float* __restrict__ b, const float* __restrict__ Wl,
    const float* __restrict__ bl, const int* __restrict__ gcur,
    unsigned* __restrict__ ebuf, int* __restrict__ ldeg,
    unsigned char* __restrict__ g8, unsigned short* __restrict__ linbuf) {
    __shared__ unsigned short WcT[128][72];   // [col][k] bf16, k padded 64->72
    __shared__ int lcnt[128];
    __shared__ int lptrS[128];
    __shared__ int lcurS[128];

    const int tid = threadIdx.x;
    {   // stage [W | Wl]^T into LDS as bf16 (W is [k][c] row-major)
        const float4* W4  = (const float4*)W;
        const float4* Wl4 = (const float4*)Wl;
        for (int i = tid; i < 1024; i += 512) {
            int k  = i >> 4;
            int c0 = (i & 15) << 2;
            float4 wv = W4[i];
            float4 lv = Wl4[i];
            WcT[c0 + 0][k] = f2bf(wv.x); WcT[c0 + 1][k] = f2bf(wv.y);
            WcT[c0 + 2][k] = f2bf(wv.z); WcT[c0 + 3][k] = f2bf(wv.w);
            WcT[64 + c0 + 0][k] = f2bf(lv.x); WcT[64 + c0 + 1][k] = f2bf(lv.y);
            WcT[64 + c0 + 2][k] = f2bf(lv.z); WcT[64 + c0 + 3][k] = f2bf(lv.w);
        }
    }
    if (tid < 128) lcnt[tid] = 0;
    __syncthreads();

    // degree histogram; keep slice entries in registers (6*512 = 3072 >= GCAP)
    const int base = blockIdx.x * GCAP;
    const int mB = gcur[blockIdx.x];
    unsigned en_[6];
#pragma unroll
    for (int i = 0; i < 6; ++i) {
        int idx = i * 512 + tid;
        if (idx < mB) {
            unsigned en = ebuf[base + idx];
            en_[i] = en;
            atomicAdd(&lcnt[en >> 17], 1);
        } else {
            en_[i] = 0xFFFFFFFFu;
        }
    }

    const int wv_  = tid >> 6;                // wave 0..7
    const int lane = tid & 63;
    const int lr   = lane & 15;
    const int lkb  = (lane >> 4) << 3;        // k base: 0,8,16,24

    const int lo   = blockIdx.x << 7;
    const int row0 = lo + wv_ * 16;

    int arow = row0 + lr;
    int arc  = arow < NN ? arow : NN - 1;
    const float* xp = x + (size_t)arc * DIM + lkb;
    float4 p0 = *(const float4*)(xp);
    float4 p1 = *(const float4*)(xp + 4);
    float4 p2 = *(const float4*)(xp + 32);
    float4 p3 = *(const float4*)(xp + 36);
    bf16x8 a0 = {(short)f2bf(p0.x), (short)f2bf(p0.y), (short)f2bf(p0.z), (short)f2bf(p0.w),
                 (short)f2bf(p1.x), (short)f2bf(p1.y), (short)f2bf(p1.z), (short)f2bf(p1.w)};
    bf16x8 a1 = {(short)f2bf(p2.x), (short)f2bf(p2.y), (short)f2bf(p2.z), (short)f2bf(p2.w),
                 (short)f2bf(p3.x), (short)f2bf(p3.y), (short)f2bf(p3.z), (short)f2bf(p3.w)};

    f32x4 acc[8];
#pragma unroll
    for (int ct = 0; ct < 8; ++ct) acc[ct] = (f32x4){0.f, 0.f, 0.f, 0.f};

#pragma unroll
    for (int ct = 0; ct < 8; ++ct) {
        bf16x8 b0 = *(const bf16x8*)&WcT[ct * 16 + lr][lkb];
        bf16x8 b1 = *(const bf16x8*)&WcT[ct * 16 + lr][32 + lkb];
        acc[ct] = __builtin_amdgcn_mfma_f32_16x16x32_bf16(a0, b0, acc[ct], 0, 0, 0);
        acc[ct] = __builtin_amdgcn_mfma_f32_16x16x32_bf16(a1, b1, acc[ct], 0, 0, 0);
    }
    __syncthreads();   // lcnt histogram complete; all ebuf reads drained

    // wave 0: exclusive-scan lcnt -> lptrS/lcurS (LDS) + ldeg (global, 129 entries)
    if (wv_ == 0) {
        int c0 = lcnt[lane];
        int c1 = lcnt[64 + lane];
        int v0 = c0;
        for (int off = 1; off < 64; off <<= 1) {
            int t = __shfl_up(v0, off);
            if (lane >= off) v0 += t;
        }
        int tot0 = __shfl(v0, 63);
        int v1 = c1;
        for (int off = 1; off < 64; off <<= 1) {
            int t = __shfl_up(v1, off);
            if (lane >= off) v1 += t;
        }
        int e0x = v0 - c0;
        int e1x = tot0 + v1 - c1;
        lptrS[lane] = e0x;      lcurS[lane] = e0x;
        lptrS[64 + lane] = e1x; lcurS[64 + lane] = e1x;
        int* lp = ldeg + blockIdx.x * LSTR;
        lp[lane] = e0x;
        lp[64 + lane] = e1x;
        if (lane == 63) lp[128] = tot0 + v1;   // total == mB
    }
    __syncthreads();   // lptrS/lcurS ready

    // placement: in-place permutation of the slice (writes after all reads)
#pragma unroll
    for (int i = 0; i < 6; ++i) {
        if (en_[i] != 0xFFFFFFFFu) {
            int ld = en_[i] >> 17;
            int pos = atomicAdd(&lcurS[ld], 1);
            ebuf[base + pos] = en_[i] & 0x1FFFFu;
        }
    }

    // epilogue
    float bcv[4];
#pragma unroll
    for (int ct = 0; ct < 4; ++ct) {
        int oc = ct * 16 + lr;
        bcv[ct] = b[oc] + bl[oc];
    }
    const int rbase = row0 + ((lane >> 4) << 2);
#pragma unroll
    for (int i = 0; i < 4; ++i) {
        int r = rbase + i;
        if (r >= NN) continue;
        float dv = rsqrtf((float)(lcnt[r - lo] + 1));
        float gv0 = acc[0][i] * dv, gv1 = acc[1][i] * dv;
        float gv2 = acc[2][i] * dv, gv3 = acc[3][i] * dv;
        unsigned w32 = __builtin_amdgcn_cvt_pk_fp8_f32(gv0, gv1, 0, false);
        w32 = (unsigned)__builtin_amdgcn_cvt_pk_fp8_f32(gv2, gv3, w32, true);
        *(unsigned*)(g8 + ((size_t)r << 6) + (lr << 2)) = w32;
        ushort4 lh;
        lh.x = f2h(acc[4][i] + bcv[0] + dv * gv0);
        lh.y = f2h(acc[5][i] + bcv[1] + dv * gv1);
        lh.z = f2h(acc[6][i] + bcv[2] + dv * gv2);
        lh.w = f2h(acc[7][i] + bcv[3] + dv * gv3);
        *(ushort4*)(linbuf + ((size_t)r << 6) + (lr << 2)) = lh;
    }
}

// ---------------- Phase B: pure gather — no LDS, no barriers ----------------
// csr (= node-sorted ebuf) + ldeg produced by k_gemm. One node per 8-lane group.

__global__ __launch_bounds__(1024, 8) void k_gatherB(
    const int* __restrict__ ldeg, const unsigned* __restrict__ csr,
    const unsigned short* __restrict__ linbuf,
    const unsigned char* __restrict__ g8, float* __restrict__ out) {
    const int tid  = threadIdx.x;
    const int node = tid >> 3;      // 0..127
    const int sub  = tid & 7;
    const int sh   = sub << 3;

    const int* lp = ldeg + blockIdx.x * LSTR;
    const int start = lp[node];
    const int end   = lp[node + 1];
    const int m = end - start;
    const unsigned* cp = csr + blockIdx.x * GCAP + start;
    const int gnode = (blockIdx.x << 7) + node;

    float a0 = 0.f, a1 = 0.f, a2 = 0.f, a3 = 0.f;
    float a4 = 0.f, a5 = 0.f, a6 = 0.f, a7 = 0.f;

    int t = 0;
    for (; t + 4 <= m; t += 4) {
        int s0 = cp[t + 0];
        int s1 = cp[t + 1];
        int s2 = cp[t + 2];
        int s3 = cp[t + 3];
        uint2 v0 = *(const uint2*)(g8 + (((size_t)s0) << 6) + sh);
        uint2 v1 = *(const uint2*)(g8 + (((size_t)s1) << 6) + sh);
        uint2 v2 = *(const uint2*)(g8 + (((size_t)s2) << 6) + sh);
        uint2 v3 = *(const uint2*)(g8 + (((size_t)s3) << 6) + sh);
        acc8(v0, a0, a1, a2, a3, a4, a5, a6, a7);
        acc8(v1, a0, a1, a2, a3, a4, a5, a6, a7);
        acc8(v2, a0, a1, a2, a3, a4, a5, a6, a7);
        acc8(v3, a0, a1, a2, a3, a4, a5, a6, a7);
    }
    for (; t < m; ++t) {
        uint2 v = *(const uint2*)(g8 + (((size_t)cp[t]) << 6) + sh);
        acc8(v, a0, a1, a2, a3, a4, a5, a6, a7);
    }

    if (gnode < NN) {
        float dv = rsqrtf((float)(m + 1));
        f16x8 lf = *(const f16x8*)(linbuf + ((size_t)gnode << 6) + sh);
        float* op = out + ((size_t)gnode << 6) + (sub << 1);
        float2 o0 = {(float)lf[0] + dv * a0, (float)lf[4] + dv * a4};
        float2 o1 = {(float)lf[1] + dv * a1, (float)lf[5] + dv * a5};
        float2 o2 = {(float)lf[2] + dv * a2, (float)lf[6] + dv * a6};
        float2 o3 = {(float)lf[3] + dv * a3, (float)lf[7] + dv * a7};
        *(float2*)(op + 0)  = o0;
        *(float2*)(op + 16) = o1;
        *(float2*)(op + 32) = o2;
        *(float2*)(op + 48) = o3;
    }
}

// ---------------- launch ----------------

extern "C" void kernel_launch(void* const* d_in, const int* in_sizes, int n_in,
                              void* d_out, int out_size, void* d_ws, size_t ws_size,
                              hipStream_t stream) {
    const float* x  = (const float*)d_in[0];
    const int*   ei = (const int*)d_in[1];
    const float* W  = (const float*)d_in[2];
    const float* b  = (const float*)d_in[3];
    const float* Wl = (const float*)d_in[4];
    const float* bl = (const float*)d_in[5];
    float* out = (float*)d_out;

    char* ws = (char*)d_ws;
    int*      gcur = (int*)(ws + 0);                       // 3128 B
    int*      ldeg = (int*)(ws + 4096);                    // 782*132*4 = 412896 B
    unsigned* ebuf = (unsigned*)(ws + 1048576);            // K*GCAP*4 = 8.13 MB (becomes csr)
    unsigned char*  g8     = (unsigned char*)(ws + 10485760);   // 6.4 MB
    unsigned short* linbuf = (unsigned short*)(ws + 17039360);  // 12.8 MB

    k_init   <<<1, 1024, 0, stream>>>(gcur);
    k_binA   <<<NTILE, 1024, 0, stream>>>(ei, gcur, ebuf);
    k_gemm   <<<K, 512, 0, stream>>>(x, W, b, Wl, bl, gcur, ebuf, ldeg, g8, linbuf);
    k_gatherB<<<K, 1024, 0, stream>>>(ldeg, ebuf, linbuf, g8, out);
}

// Round 19
// 66.297 us; speedup vs baseline: 1.1159x; 1.1159x over previous
//
#include <hip/hip_runtime.h>

#define NN 100000
#define NE 1600000
#define DIM 64
#define K 782            // buckets of 128 nodes: b = dst >> 7
#define ABLK 6250        // edges per binning tile; NE = 256 * 6250 exactly
#define NTILE 256        // one binA block per CU
#define GCAP 2600        // fixed per-bucket capacity (mean 2048, sigma 45, 12+ sigma)

typedef __attribute__((ext_vector_type(8))) short bf16x8;
typedef __attribute__((ext_vector_type(8))) _Float16 f16x8;
typedef __attribute__((ext_vector_type(2))) float f32x2;
typedef __attribute__((ext_vector_type(4))) float f32x4;

__device__ __forceinline__ unsigned short f2bf(float f) {
    union { float f; unsigned u; } c; c.f = f;
    unsigned r = (c.u + 0x7FFFu + ((c.u >> 16) & 1u)) >> 16;   // RNE
    return (unsigned short)r;
}
__device__ __forceinline__ unsigned short f2h(float f) {
    union { _Float16 h; unsigned short u; } c; c.h = (_Float16)f;
    return c.u;
}
__device__ __forceinline__ void acc8(uint2 v, float& a0, float& a1, float& a2, float& a3,
                                     float& a4, float& a5, float& a6, float& a7) {
    f32x2 d0 = __builtin_amdgcn_cvt_pk_f32_fp8(v.x, false);
    f32x2 d1 = __builtin_amdgcn_cvt_pk_f32_fp8(v.x, true);
    f32x2 d2 = __builtin_amdgcn_cvt_pk_f32_fp8(v.y, false);
    f32x2 d3 = __builtin_amdgcn_cvt_pk_f32_fp8(v.y, true);
    a0 += d0.x; a1 += d0.y; a2 += d1.x; a3 += d1.y;
    a4 += d2.x; a5 += d2.y; a6 += d3.x; a7 += d3.y;
}

// ---------------- init fixed bucket cursors ----------------

__global__ void k_init(int* __restrict__ gcur) {
    int i = blockIdx.x * blockDim.x + threadIdx.x;
    if (i < K) gcur[i] = 0;
}

// ---------------- Phase A: bin edges by bucket, coalesced run writes ----------------

__global__ __launch_bounds__(1024) void k_binA(const int* __restrict__ ei,
                                               int* __restrict__ gcur,
                                               unsigned* __restrict__ ebuf) {
    __shared__ int hist[1024];               // per-bucket counts (only [0..K) used)
    __shared__ int wsum[16];
    __shared__ int hoff[K];                  // run start within tile
    __shared__ int gbase[K];                 // claimed global base (absolute)
    __shared__ int lcur[K];
    __shared__ unsigned sbufE[ABLK];         // packed (ldst<<17)|src, bucket-sorted
    __shared__ unsigned short sbufB[ABLK];   // bucket id per entry

    const int tid = threadIdx.x;
    const int e0 = blockIdx.x * ABLK;

    hist[tid] = 0;
    __syncthreads();

    // pass 1: count (keep edges in registers); NE = NTILE*ABLK exactly
    int pk_[7]; int b_[7]; int myN = 0;
#pragma unroll
    for (int i = 0; i < 7; ++i) {
        int j = i * 1024 + tid;
        if (j < ABLK) {
            int e = e0 + j;
            int dst = ei[NE + e];
            int src = ei[e];
            int b = dst >> 7;
            pk_[myN]  = ((dst & 127) << 17) | src;
            b_[myN]   = b;
            ++myN;
            atomicAdd(&hist[b], 1);
        }
    }
    __syncthreads();

    // wave-level scan of hist (3 barriers total)
    const int lane = tid & 63;
    const int wid  = tid >> 6;
    int cntv = hist[tid];
    int v = cntv;
#pragma unroll
    for (int off = 1; off < 64; off <<= 1) {
        int t = __shfl_up(v, off);
        if (lane >= off) v += t;
    }
    if (lane == 63) wsum[wid] = v;
    __syncthreads();
    int woff = 0;
#pragma unroll
    for (int u = 0; u < 15; ++u) {
        if (u < wid) woff += wsum[u];
    }
    if (tid < K) {
        int incl = v + woff;
        int ho = incl - cntv;
        hoff[tid] = ho;
        lcur[tid] = ho;
        int claimed = (cntv > 0) ? atomicAdd(&gcur[tid], cntv) : 0;
        gbase[tid] = tid * GCAP + claimed;
    }
    __syncthreads();

    // pass 2: place into LDS, bucket-sorted
    for (int j = 0; j < myN; ++j) {
        int pos = atomicAdd(&lcur[b_[j]], 1);
        sbufE[pos] = (unsigned)pk_[j];
        sbufB[pos] = (unsigned short)b_[j];
    }
    __syncthreads();

    // pass 3: coalesced run writes
    for (int j = tid; j < ABLK; j += 1024) {
        unsigned en = sbufE[j];
        int b = sbufB[j];
        ebuf[gbase[b] + (j - hoff[b])] = en;
    }
}

// ---------------- MFMA dense, 1 block = 1 bucket (128 rows, 512 thr) ----------------
// Swizzled stores: position p = lr*4+ct  <->  col = (p&3)*16 + (p>>2).
// g8[r][p]  = fp8(dinv*xW col); lin[r][p] = f16(xWl + b + bl + dinv^2*xW col).
// Forwards per-node CSR offsets (ldeg) to gatherB via wave-0 shfl scan.

__global__ __launch_bounds__(512) void k_gemm(
    const float* __restrict__ x, const float* __restrict__ W,
    const float* __restrict__ b, const float* __restrict__ Wl,
    const float* __restrict__ bl, const int* __restrict__ gcur,
    const unsigned* __restrict__ ebuf, int* __restrict__ ldeg,
    unsigned char* __restrict__ g8, unsigned short* __restrict__ linbuf) {
    __shared__ unsigned short WcT[128][72];   // [col][k] bf16, k padded 64->72
    __shared__ int lcnt[128];

    const int tid = threadIdx.x;
    {   // stage [W | Wl]^T into LDS as bf16 (W is [k][c] row-major)
        const float4* W4  = (const float4*)W;
        const float4* Wl4 = (const float4*)Wl;
        for (int i = tid; i < 1024; i += 512) {
            int k  = i >> 4;
            int c0 = (i & 15) << 2;
            float4 wv = W4[i];
            float4 lv = Wl4[i];
            WcT[c0 + 0][k] = f2bf(wv.x); WcT[c0 + 1][k] = f2bf(wv.y);
            WcT[c0 + 2][k] = f2bf(wv.z); WcT[c0 + 3][k] = f2bf(wv.w);
            WcT[64 + c0 + 0][k] = f2bf(lv.x); WcT[64 + c0 + 1][k] = f2bf(lv.y);
            WcT[64 + c0 + 2][k] = f2bf(lv.z); WcT[64 + c0 + 3][k] = f2bf(lv.w);
        }
    }
    if (tid < 128) lcnt[tid] = 0;
    __syncthreads();

    // in-block degree histogram of this bucket's ebuf slice
    const int base = blockIdx.x * GCAP;
    const int mB = gcur[blockIdx.x];
    for (int i = tid; i < mB; i += 512) {
        atomicAdd(&lcnt[ebuf[base + i] >> 17], 1);
    }

    const int wv_  = tid >> 6;                // wave 0..7
    const int lane = tid & 63;
    const int lr   = lane & 15;
    const int lkb  = (lane >> 4) << 3;        // k base: 0,8,16,24

    const int lo   = blockIdx.x << 7;
    const int row0 = lo + wv_ * 16;

    int arow = row0 + lr;
    int arc  = arow < NN ? arow : NN - 1;
    const float* xp = x + (size_t)arc * DIM + lkb;
    float4 p0 = *(const float4*)(xp);
    float4 p1 = *(const float4*)(xp + 4);
    float4 p2 = *(const float4*)(xp + 32);
    float4 p3 = *(const float4*)(xp + 36);
    bf16x8 a0 = {(short)f2bf(p0.x), (short)f2bf(p0.y), (short)f2bf(p0.z), (short)f2bf(p0.w),
                 (short)f2bf(p1.x), (short)f2bf(p1.y), (short)f2bf(p1.z), (short)f2bf(p1.w)};
    bf16x8 a1 = {(short)f2bf(p2.x), (short)f2bf(p2.y), (short)f2bf(p2.z), (short)f2bf(p2.w),
                 (short)f2bf(p3.x), (short)f2bf(p3.y), (short)f2bf(p3.z), (short)f2bf(p3.w)};

    f32x4 acc[8];
#pragma unroll
    for (int ct = 0; ct < 8; ++ct) acc[ct] = (f32x4){0.f, 0.f, 0.f, 0.f};

#pragma unroll
    for (int ct = 0; ct < 8; ++ct) {
        bf16x8 b0 = *(const bf16x8*)&WcT[ct * 16 + lr][lkb];
        bf16x8 b1 = *(const bf16x8*)&WcT[ct * 16 + lr][32 + lkb];
        acc[ct] = __builtin_amdgcn_mfma_f32_16x16x32_bf16(a0, b0, acc[ct], 0, 0, 0);
        acc[ct] = __builtin_amdgcn_mfma_f32_16x16x32_bf16(a1, b1, acc[ct], 0, 0, 0);
    }
    __syncthreads();   // lcnt histogram complete

    // wave 0: exclusive-scan lcnt[0..127] via shfl, forward to gatherB
    if (wv_ == 0) {
        int c0 = lcnt[lane];
        int c1 = lcnt[64 + lane];
        int v0 = c0;
        for (int off = 1; off < 64; off <<= 1) {
            int t = __shfl_up(v0, off);
            if (lane >= off) v0 += t;
        }
        int tot0 = __shfl(v0, 63);
        int v1 = c1;
        for (int off = 1; off < 64; off <<= 1) {
            int t = __shfl_up(v1, off);
            if (lane >= off) v1 += t;
        }
        int* lp = ldeg + blockIdx.x * 128;
        lp[lane] = v0 - c0;
        lp[64 + lane] = tot0 + v1 - c1;
    }

    float bcv[4];
#pragma unroll
    for (int ct = 0; ct < 4; ++ct) {
        int oc = ct * 16 + lr;
        bcv[ct] = b[oc] + bl[oc];
    }
    const int rbase = row0 + ((lane >> 4) << 2);
#pragma unroll
    for (int i = 0; i < 4; ++i) {
        int r = rbase + i;
        if (r >= NN) continue;
        float dv = rsqrtf((float)(lcnt[r - lo] + 1));
        float gv0 = acc[0][i] * dv, gv1 = acc[1][i] * dv;
        float gv2 = acc[2][i] * dv, gv3 = acc[3][i] * dv;
        unsigned w32 = __builtin_amdgcn_cvt_pk_fp8_f32(gv0, gv1, 0, false);
        w32 = (unsigned)__builtin_amdgcn_cvt_pk_fp8_f32(gv2, gv3, w32, true);
        *(unsigned*)(g8 + ((size_t)r << 6) + (lr << 2)) = w32;
        ushort4 lh;
        lh.x = f2h(acc[4][i] + bcv[0] + dv * gv0);
        lh.y = f2h(acc[5][i] + bcv[1] + dv * gv1);
        lh.z = f2h(acc[6][i] + bcv[2] + dv * gv2);
        lh.w = f2h(acc[7][i] + bcv[3] + dv * gv3);
        *(ushort4*)(linbuf + ((size_t)r << 6) + (lr << 2)) = lh;
    }
}

// ---------------- Phase B: placement + gather, 1024 thr (16 waves), 1 node per
// 8-lane group. VGPR capped at 64 via launch_bounds -> 2 blocks/CU = 32 waves/CU.

__global__ __launch_bounds__(1024, 8) void k_gatherB(
    const int* __restrict__ gcur, const unsigned* __restrict__ ebuf,
    const int* __restrict__ ldeg, const unsigned short* __restrict__ linbuf,
    const unsigned char* __restrict__ g8, float* __restrict__ out) {
    __shared__ int lptr[128];
    __shared__ int lcur[128];
    __shared__ unsigned lsrc[GCAP];

    const int tid = threadIdx.x;
    const int lo = blockIdx.x << 7;
    const int base = blockIdx.x * GCAP;
    const int mB = gcur[blockIdx.x];

    if (tid < 128) {
        int v = ldeg[blockIdx.x * 128 + tid];
        lptr[tid] = v;
        lcur[tid] = v;
    }
    __syncthreads();

    // placement pass (2 rounds at 1024 threads)
    for (int i = tid; i < mB; i += 1024) {
        unsigned en = ebuf[base + i];
        int ld = en >> 17;
        int pos = atomicAdd(&lcur[ld], 1);
        lsrc[pos] = en & 0x1FFFFu;
    }
    __syncthreads();

    const int node = tid >> 3;      // 0..127: one node per 8-lane group
    const int sub  = tid & 7;
    const int sh   = sub << 3;

    const int gnode = lo + node;
    const int start = lptr[node];
    const int m = lcur[node] - start;

    float a0 = 0.f, a1 = 0.f, a2 = 0.f, a3 = 0.f;
    float a4 = 0.f, a5 = 0.f, a6 = 0.f, a7 = 0.f;

    int t = 0;
    for (; t + 4 <= m; t += 4) {
        int s0 = lsrc[start + t + 0];
        int s1 = lsrc[start + t + 1];
        int s2 = lsrc[start + t + 2];
        int s3 = lsrc[start + t + 3];
        uint2 v0 = *(const uint2*)(g8 + (((size_t)s0) << 6) + sh);
        uint2 v1 = *(const uint2*)(g8 + (((size_t)s1) << 6) + sh);
        uint2 v2 = *(const uint2*)(g8 + (((size_t)s2) << 6) + sh);
        uint2 v3 = *(const uint2*)(g8 + (((size_t)s3) << 6) + sh);
        acc8(v0, a0, a1, a2, a3, a4, a5, a6, a7);
        acc8(v1, a0, a1, a2, a3, a4, a5, a6, a7);
        acc8(v2, a0, a1, a2, a3, a4, a5, a6, a7);
        acc8(v3, a0, a1, a2, a3, a4, a5, a6, a7);
    }
    for (; t < m; ++t) {
        uint2 v = *(const uint2*)(g8 + (((size_t)lsrc[start + t]) << 6) + sh);
        acc8(v, a0, a1, a2, a3, a4, a5, a6, a7);
    }

    if (gnode < NN) {
        float dv = rsqrtf((float)(m + 1));
        f16x8 lf = *(const f16x8*)(linbuf + ((size_t)gnode << 6) + sh);
        float* op = out + ((size_t)gnode << 6) + (sub << 1);
        float2 o0 = {(float)lf[0] + dv * a0, (float)lf[4] + dv * a4};
        float2 o1 = {(float)lf[1] + dv * a1, (float)lf[5] + dv * a5};
        float2 o2 = {(float)lf[2] + dv * a2, (float)lf[6] + dv * a6};
        float2 o3 = {(float)lf[3] + dv * a3, (float)lf[7] + dv * a7};
        *(float2*)(op + 0)  = o0;
        *(float2*)(op + 16) = o1;
        *(float2*)(op + 32) = o2;
        *(float2*)(op + 48) = o3;
    }
}

// ---------------- launch ----------------

extern "C" void kernel_launch(void* const* d_in, const int* in_sizes, int n_in,
                              void* d_out, int out_size, void* d_ws, size_t ws_size,
                              hipStream_t stream) {
    const float* x  = (const float*)d_in[0];
    const int*   ei = (const int*)d_in[1];
    const float* W  = (const float*)d_in[2];
    const float* b  = (const float*)d_in[3];
    const float* Wl = (const float*)d_in[4];
    const float* bl = (const float*)d_in[5];
    float* out = (float*)d_out;

    char* ws = (char*)d_ws;
    int*      gcur = (int*)(ws + 0);                       // 3128 B
    int*      ldeg = (int*)(ws + 4096);                    // 400384 B
    unsigned* ebuf = (unsigned*)(ws + 1048576);            // K*GCAP*4 = 8.13 MB
    unsigned char*  g8     = (unsigned char*)(ws + 10485760);   // 6.4 MB
    unsigned short* linbuf = (unsigned short*)(ws + 17039360);  // 12.8 MB

    k_init   <<<1, 1024, 0, stream>>>(gcur);
    k_binA   <<<NTILE, 1024, 0, stream>>>(ei, gcur, ebuf);
    k_gemm   <<<K, 512, 0, stream>>>(x, W, b, Wl, bl, gcur, ebuf, ldeg, g8, linbuf);
    k_gatherB<<<K, 1024, 0, stream>>>(gcur, ebuf, ldeg, linbuf, g8, out);
}